// Round 12
// baseline (150.102 us; speedup 1.0000x reference)
//
#include <hip/hip_runtime.h>
#include <math.h>

// LocalContrastNormalization: out = sigmoid(0.5*(x-mu)/(sigma+eps)),
// mu/sigma from 31x31 zero-padded box filter (separable).
// v12: 4 BARRIER DOMAINS PER CU. Half-width blocks (CW=512, SH=64) ->
// grid 1024 -> 4 blocks/CU, 20 waves/CU (NT=320). Producer/consumer split:
//  - producers: threads 0..135, each owns a 4-col group of the 544-col range
//    [x0-16, x0+528) (halo cols recomputed; col-masks make image-edge zeros,
//    so no LDS pad init is needed at all). Register sliding vertical sums,
//    prefetch one phase ahead, publish into double-buffered transposed LDS.
//  - consumers: waves 3..4; each wave owns TWO rows per phase (lanes 0..31 =
//    row A, lanes 32..63 = row B, 16 cols = 64 B per lane) -> every x-load /
//    store instruction covers full 64B sectors in two dense 2KB runs (keeps
//    the proven exact-131MB write pattern at half width).
//  - 3-trans pointwise: rsqrt + linear eps-correction replaces sqrt+rcp.
//  - lgkm-only barriers, one per phase; roles branch INSIDE a uniform loop.
// LDS = 2 x 4 x 544 float2 = 34.8 KB -> 4 blocks/CU.

#define KSZ    31
#define PAD    15
#define IMG_H  1024
#define IMG_W  1024
#define SH     64                // rows per block
#define CW     512               // interior cols per block
#define GP     4                 // rows per phase
#define NPH    (SH / GP)         // 16
#define NT     320               // 5 waves: producers in 0..2, consumers 3..4
#define NPROD  136               // 136 threads x 4 cols = 544 = 512 + 2*16
#define LROW   34                // transposed stride in float2 units
#define SLOT   (16 * LROW)       // 544 float2 per row-slot
#define EPSV   1e-5f

// LDS-only barrier: orders ds ops across waves WITHOUT draining in-flight
// global loads (they only feed private registers).
#define LDS_BARRIER() do {                                   \
    asm volatile("s_waitcnt lgkmcnt(0)" ::: "memory");       \
    __builtin_amdgcn_s_barrier();                            \
} while (0)

__global__ __launch_bounds__(NT, 5)
void lcn_fused_kernel(const float* __restrict__ x, float* __restrict__ out) {
    // XCD-aware bijective swizzle (gridDim.x = 1024, %8==0): 128 consecutive
    // work-ids (= 2 full images) per XCD -> halo re-reads are L2-local.
    const int cpx = gridDim.x >> 3;
    const int bid = (blockIdx.x & 7) * cpx + (blockIdx.x >> 3);

    const int xc = bid & 1;                // 2 x-chunks
    const int yc = (bid >> 1) & 15;        // 16 y-chunks
    const int b  = bid >> 5;               // image
    const int y0 = yc * SH;
    const int x0 = xc * CW;

    const float* img  = x   + (size_t)b * (IMG_H * IMG_W);
    float*       oimg = out + (size_t)b * (IMG_H * IMG_W);

    __shared__ float2 vbuf[2][GP][SLOT];   // double-buffered, transposed

    const int t = threadIdx.x;
    const bool is_prod = (t < NPROD);
    const bool is_cons = (t >= 192);
    const float inv = 1.0f / 961.0f;

    // ---------- producer persistent state ----------
    float vs0=0,vs1=0,vs2=0,vs3=0, vq0=0,vq1=0,vq2=0,vq3=0;
    float4 pfS[GP], pfA[GP];
    int wp0=0, wp1=0, wp2=0, wp3=0, ga=0;
    float cmf = 0.f;

    if (is_prod) {
        const int gc0 = x0 - 16 + 4 * t;           // group col base
        const bool cm = (gc0 >= 0) && (gc0 < IMG_W);
        ga  = cm ? gc0 : 0;
        cmf = cm ? 1.f : 0.f;
        const int iv = 4 * t;                      // iv = col - x0 + 16
        wp0 = ((iv    ) & 15) * LROW + ((iv    ) >> 4);
        wp1 = ((iv + 1) & 15) * LROW + ((iv + 1) >> 4);
        wp2 = ((iv + 2) & 15) * LROW + ((iv + 2) >> 4);
        wp3 = ((iv + 3) & 15) * LROW + ((iv + 3) >> 4);

        // Vertical warm-up: window(y0) over rows [y0-15, y0+15].
        for (int y = y0 - PAD; y <= y0 + PAD; ++y) {
            const int ycl = max(y, 0);
            float4 v = *(const float4*)(img + (size_t)ycl * IMG_W + ga);
            const float m = ((y >= 0) ? 1.f : 0.f) * cmf;
            v.x *= m; v.y *= m; v.z *= m; v.w *= m;
            vs0 += v.x; vq0 = fmaf(v.x, v.x, vq0);
            vs1 += v.y; vq1 = fmaf(v.y, v.y, vq1);
            vs2 += v.z; vq2 = fmaf(v.z, v.z, vq2);
            vs3 += v.w; vq3 = fmaf(v.w, v.w, vq3);
        }

        // Prologue: publish G0 (rows y0..y0+3) into buf0, sliding directly.
        #pragma unroll
        for (int r = 0; r < GP; ++r) {
            vbuf[0][r][wp0] = make_float2(vs0, vq0);
            vbuf[0][r][wp1] = make_float2(vs1, vq1);
            vbuf[0][r][wp2] = make_float2(vs2, vq2);
            vbuf[0][r][wp3] = make_float2(vs3, vq3);
            const int ys  = y0 + r - PAD;
            const int ya  = y0 + r + PAD + 1;      // <= y0+19: never clips
            const int ysc = max(ys, 0);
            float4 vS = *(const float4*)(img + (size_t)ysc * IMG_W + ga);
            float4 vA = *(const float4*)(img + (size_t)ya  * IMG_W + ga);
            const float mS = ((ys >= 0) ? 1.f : 0.f) * cmf;
            float s0 = vS.x*mS, s1 = vS.y*mS, s2 = vS.z*mS, s3 = vS.w*mS;
            float a0 = vA.x*cmf, a1 = vA.y*cmf, a2 = vA.z*cmf, a3 = vA.w*cmf;
            vs0 += a0 - s0; vq0 = fmaf(a0, a0, vq0); vq0 = fmaf(-s0, s0, vq0);
            vs1 += a1 - s1; vq1 = fmaf(a1, a1, vq1); vq1 = fmaf(-s1, s1, vq1);
            vs2 += a2 - s2; vq2 = fmaf(a2, a2, vq2); vq2 = fmaf(-s2, s2, vq2);
            vs3 += a3 - s3; vq3 = fmaf(a3, a3, vq3); vq3 = fmaf(-s3, s3, vq3);
        }

        // Prefetch slide rows for phase 0's publish (base y0+GP).
        {
            const int base = y0 + GP;
            #pragma unroll
            for (int r = 0; r < GP; ++r) {
                const int ys = base + r - PAD;
                const int ya = base + r + PAD + 1;
                pfS[r] = *(const float4*)(img + (size_t)max(ys, 0) * IMG_W + ga);
                pfA[r] = *(const float4*)(img + (size_t)min(ya, IMG_H - 1) * IMG_W + ga);
            }
        }
    }

    // Consumer constants.
    const int lane = t & 63;
    const int cw   = (t >> 6) - 3;          // 0/1 (consumers only)
    const int rsub = lane >> 5;             // row within pair
    const int lcol = (lane & 31) << 4;      // 16 cols per lane

    for (int p = 0; p < NPH; ++p) {
        LDS_BARRIER();   // buf[p&1] complete; loads stay in flight

        if (is_prod) {
            if (p < NPH - 1) {
                const int base = y0 + GP * (p + 1);
                float2* dst = &vbuf[(p + 1) & 1][0][0];
                #pragma unroll
                for (int r = 0; r < GP; ++r) {
                    float2* d = dst + r * SLOT;
                    d[wp0] = make_float2(vs0, vq0);
                    d[wp1] = make_float2(vs1, vq1);
                    d[wp2] = make_float2(vs2, vq2);
                    d[wp3] = make_float2(vs3, vq3);
                    const int ys = base + r - PAD;
                    const int ya = base + r + PAD + 1;
                    const float mS = ((ys >= 0)    ? 1.f : 0.f) * cmf;
                    const float mA = ((ya < IMG_H) ? 1.f : 0.f) * cmf;
                    float s0 = pfS[r].x*mS, s1 = pfS[r].y*mS,
                          s2 = pfS[r].z*mS, s3 = pfS[r].w*mS;
                    float a0 = pfA[r].x*mA, a1 = pfA[r].y*mA,
                          a2 = pfA[r].z*mA, a3 = pfA[r].w*mA;
                    vs0 += a0 - s0; vq0 = fmaf(a0, a0, vq0); vq0 = fmaf(-s0, s0, vq0);
                    vs1 += a1 - s1; vq1 = fmaf(a1, a1, vq1); vq1 = fmaf(-s1, s1, vq1);
                    vs2 += a2 - s2; vq2 = fmaf(a2, a2, vq2); vq2 = fmaf(-s2, s2, vq2);
                    vs3 += a3 - s3; vq3 = fmaf(a3, a3, vq3); vq3 = fmaf(-s3, s3, vq3);
                }
                if (p < NPH - 2) {           // prefetch for next publish
                    const int base2 = y0 + GP * (p + 2);
                    #pragma unroll
                    for (int r = 0; r < GP; ++r) {
                        const int ys = base2 + r - PAD;
                        const int ya = base2 + r + PAD + 1;
                        pfS[r] = *(const float4*)(img + (size_t)max(ys, 0) * IMG_W + ga);
                        pfA[r] = *(const float4*)(img + (size_t)min(ya, IMG_H - 1) * IMG_W + ga);
                    }
                }
            }
        } else if (is_cons) {
            const int r   = 2 * cw + rsub;            // slot 0..3
            const int row = y0 + GP * p + r;

            // x loads: lanes 0..31 dense 2KB (row A) + lanes 32..63 (row B).
            const float* xr = img + (size_t)row * IMG_W + x0 + lcol;
            float4 xa = ((const float4*)xr)[0];
            float4 xb = ((const float4*)xr)[1];
            float4 xc2 = ((const float4*)xr)[2];
            float4 xd = ((const float4*)xr)[3];

            const float2* vr = &vbuf[p & 1][r][lane & 31];

            // Warm-up: window of local col lcol = iv lcol+1 .. lcol+31.
            float hs = 0.f, hq = 0.f;
            #pragma unroll
            for (int s = 1; s <= 31; ++s) {
                float2 v = vr[(s & 15) * LROW + (s >> 4)];
                hs += v.x; hq += v.y;
            }
            float xs[16] = { xa.x, xa.y, xa.z, xa.w,  xb.x, xb.y, xb.z, xb.w,
                             xc2.x, xc2.y, xc2.z, xc2.w,  xd.x, xd.y, xd.z, xd.w };
            float res[16];
            #pragma unroll
            for (int j = 0; j < 16; ++j) {
                if (j > 0) {
                    float2 va  = vr[((j - 1) & 15) * LROW + 2];  // iv=lcol+j+31
                    float2 vsu = vr[(j & 15) * LROW];            // iv=lcol+j
                    hs += va.x - vsu.x;
                    hq += va.y - vsu.y;
                }
                const float mean = hs * inv;
                const float var  = fmaf(-mean, mean, hq * inv);
                const float vc   = fmaxf(var, EPSV);
                const float tr   = __builtin_amdgcn_rsqf(vc);    // 1/sqrt(vc)
                const float dinv = tr - (EPSV * tr) * tr;        // ~1/(std+eps)
                const float norm = (xs[j] - mean) * dinv;
                res[j] = __builtin_amdgcn_rcpf(1.0f + __expf(-0.5f * norm));
            }

            // Dense 64B/lane stores: full-sector coverage per instruction.
            float* orow = oimg + (size_t)row * IMG_W + x0 + lcol;
            ((float4*)orow)[0] = make_float4(res[0],  res[1],  res[2],  res[3]);
            ((float4*)orow)[1] = make_float4(res[4],  res[5],  res[6],  res[7]);
            ((float4*)orow)[2] = make_float4(res[8],  res[9],  res[10], res[11]);
            ((float4*)orow)[3] = make_float4(res[12], res[13], res[14], res[15]);
        }
        // threads 136..191: barrier-only idlers (uniform loop, no divergence
        // around the barrier).
    }
}

extern "C" void kernel_launch(void* const* d_in, const int* in_sizes, int n_in,
                              void* d_out, int out_size, void* d_ws, size_t ws_size,
                              hipStream_t stream) {
    (void)n_in; (void)out_size; (void)d_ws; (void)ws_size;
    const float* x = (const float*)d_in[0];
    float* out = (float*)d_out;
    const int B = in_sizes[0] / (IMG_H * IMG_W);            // 32
    dim3 grid(B * (IMG_H / SH) * (IMG_W / CW));             // 1024 blocks
    lcn_fused_kernel<<<grid, NT, 0, stream>>>(x, out);
}